// Round 12
// baseline (566.205 us; speedup 1.0000x reference)
//
#include <hip/hip_runtime.h>
#include <cstdint>
#include <cstddef>

#define Bn 8
#define Tn 8192
#define BT (Bn*Tn)      // 65536 points
#define Hn 128
#define RRn 16384       // 128*128 bins per plane per batch

typedef unsigned short u16;
typedef __attribute__((ext_vector_type(8))) short s8v;   // 8 bf16 (4 VGPRs)
typedef __attribute__((ext_vector_type(4))) float f4v;   // 4 f32 acc

#define SSTR ((size_t)BT*128)   // per-stream activation stride (elements)

__device__ __forceinline__ u16 f2bf(float f) {
  unsigned u = __float_as_uint(f);
  unsigned r = (u + 0x7FFF + ((u >> 16) & 1)) >> 16;   // RNE
  return (u16)r;
}
__device__ __forceinline__ unsigned pack2(float a, float b) {
  return (unsigned)f2bf(a) | ((unsigned)f2bf(b) << 16);
}

__device__ __forceinline__ s8v relu8(s8v a) {
  union { s8v s; unsigned u[4]; } x; x.s = a;
#pragma unroll
  for (int k = 0; k < 4; ++k) {
    unsigned m = ((x.u[k] & 0x80008000u) >> 15) * 0xFFFFu;
    x.u[k] &= ~m;
  }
  return x.s;
}

__device__ __forceinline__ void upk(unsigned u, float& lo, float& hi) {
  lo = __uint_as_float(u << 16);
  hi = __uint_as_float(u & 0xFFFF0000u);
}

// ---------------- index computation + histogram ----------------
__global__ void k_idx(const float* __restrict__ p, int* __restrict__ idx,
                      int* __restrict__ cnt32) {
  int i = blockIdx.x*256 + threadIdx.x;
  if (i >= BT) return;
  int b = i >> 13;
  float v0 = p[i*3+0], v1 = p[i*3+1], v2 = p[i*3+2];
  float v[3] = {v0, v1, v2};
  const int A0[3] = {0,0,1};
  const int A1[3] = {2,1,2};
#pragma unroll
  for (int pl = 0; pl < 3; ++pl) {
    float a = v[A0[pl]] / 1.001f + 0.5f;
    float bq = v[A1[pl]] / 1.001f + 0.5f;
    a = fminf(fmaxf(a, 0.0f), 0.999f);
    bq = fminf(fmaxf(bq, 0.0f), 0.999f);
    int ga = (int)floorf(a * 128.0f);
    int gb = (int)floorf(bq * 128.0f);
    int bin = ga + 128*gb;
    idx[pl*BT + i] = bin;
    atomicAdd(&cnt32[(pl*Bn + b)*RRn + bin], 1);
  }
}

// ---------------- CSR build ----------------
__global__ void k_scan(const int* __restrict__ cnt32, int* __restrict__ starts,
                       int* __restrict__ cursor) {
  int seg = blockIdx.x;                 // 0..23
  const int* c = cnt32 + seg*RRn;
  int* st = starts + seg*RRn;
  int* cu = cursor + seg*RRn;
  int t = threadIdx.x;
  __shared__ int part[256];
  int base = t*64;
  int sum = 0;
#pragma unroll 8
  for (int j = 0; j < 64; ++j) sum += c[base+j];
  part[t] = sum; __syncthreads();
  for (int ofs = 1; ofs < 256; ofs <<= 1) {
    int v = (t >= ofs) ? part[t-ofs] : 0;
    __syncthreads();
    part[t] += v;
    __syncthreads();
  }
  int run = (t ? part[t-1] : 0) + seg*Tn;
#pragma unroll 8
  for (int j = 0; j < 64; ++j) { st[base+j] = run; cu[base+j] = run; run += c[base+j]; }
}

__global__ void k_fill(const int* __restrict__ idx, int* __restrict__ cursor,
                       int* __restrict__ sorted) {
  int g = blockIdx.x*256 + threadIdx.x;
  if (g >= 3*BT) return;
  int pl = g >> 16, i = g & (BT-1);
  int b = i >> 13;
  int pos = atomicAdd(&cursor[(pl*Bn + b)*RRn + idx[g]], 1);
  sorted[pos] = i;
}

// ---------------- weight prep: f32 [k][n] -> bf16 [n][k], 52 chunks of 128x128 ----
__global__ void k_prep(const float* __restrict__ bw0, const float* __restrict__ bw1,
                       const float* __restrict__ bws, const float* __restrict__ cw0,
                       const float* __restrict__ cw1, const float* __restrict__ cws,
                       const float* __restrict__ fcw, const float* __restrict__ fccw,
                       u16* __restrict__ arena) {
  int c = blockIdx.x;            // 0..51
  int s = c / 26, r = c % 26;
  const float* base;
  if (r < 10)      base = (s ? cw0 : bw0) + (size_t)(r >> 1)*32768 + (size_t)(r & 1)*16384;
  else if (r < 15) base = (s ? cw1 : bw1) + (size_t)(r - 10)*16384;
  else if (r < 25) base = (s ? cws : bws) + (size_t)((r - 15) >> 1)*32768 + (size_t)((r - 15) & 1)*16384;
  else             base = s ? fccw : fcw;
  __shared__ u16 ld[128*130];
#pragma unroll 4
  for (int it = 0; it < 64; ++it) {
    int lin = it*256 + threadIdx.x;
    int k = lin >> 7, n = lin & 127;
    ld[k*130 + n] = f2bf(base[lin]);
  }
  __syncthreads();
  u16* dst = arena + (size_t)c*16384;
#pragma unroll 4
  for (int it = 0; it < 64; ++it) {
    int lin = it*256 + threadIdx.x;
    int n = lin >> 7, k = lin & 127;
    dst[lin] = ld[k*130 + n];
  }
}

// ---------------- fused ResNet block, 128 rows/block, 70 KB LDS -> 2 blocks/CU ---
// MODE 1: block 0 -- x = projection computed in staging.
// MODE 0: middle  -- x = [xA | xB] from global (xB = pooled from k_pool).
// MODE 2: final   -- like 0, plus fused final FC.
// hidden = relu( relu(x) @ w0 + b0 )   (LDS only; hid aliases xs)
// out    = x @ ws + hidden @ w1 + b1   [; cout = out @ fcw + fcb in MODE 2]
template<int MODE>
__global__ __launch_bounds__(512, 4) void k_rb(
    const u16* __restrict__ xAb, const u16* __restrict__ xBb,
    const float* __restrict__ p, const float* __restrict__ p2,
    const float* __restrict__ wp, const float* __restrict__ bp,
    const float* __restrict__ wp2, const float* __restrict__ bp2,
    const u16* __restrict__ arena,
    int cw00, int cw01, int cws0, int cws1, int cw1c, int cfcw,
    const float* __restrict__ b0g, const float* __restrict__ b0c,
    const float* __restrict__ b1g, const float* __restrict__ b1c,
    const float* __restrict__ fcbg, const float* __restrict__ fcbc,
    u16* __restrict__ outb)
{
  const int y = blockIdx.y;
  const u16* ar = arena + (size_t)y*26*16384;
  const u16* w00 = ar + (size_t)cw00*16384;
  const u16* w01 = ar + (size_t)cw01*16384;
  const u16* ws0 = ar + (size_t)cws0*16384;
  const u16* ws1 = ar + (size_t)cws1*16384;
  const u16* w1c = ar + (size_t)cw1c*16384;
  const u16* fcw = ar + (size_t)cfcw*16384;
  const float* b0 = y ? b0c : b0g;
  const float* b1 = y ? b1c : b1g;
  const float* fcb = y ? fcbc : fcbg;
  const u16* xA = xAb + (size_t)y*SSTR;
  const u16* xB = xBb + (size_t)y*SSTR;
  u16* outp = outb + (size_t)y*SSTR;

  __shared__ u16 uni[128*136];  // xs (stride 72) during kc loop; hid (stride 136) after
  __shared__ u16 w0s[128*72];   // fc0 weight chunk [n][k]  -> later w1 lo / fcw lo
  __shared__ u16 wss[128*72];   // shortcut weight chunk    -> later w1 hi / fcw hi
  u16* xs  = uni;
  u16* hid = uni;
  const int tid = threadIdx.x;
  const size_t row0 = (size_t)blockIdx.x * 128;
  const int l = tid & 63, w = tid >> 6;     // 8 waves, 16 rows each
  const int lm = l & 15, lg = l >> 4;
  const int trow = tid >> 2, tq = tid & 3;  // staging: 4 thr/row, 32B each

  f4v acc_h[8], acc_s[8];
#pragma unroll
  for (int j = 0; j < 8; ++j) { acc_h[j] = (f4v){0,0,0,0}; acc_s[j] = (f4v){0,0,0,0}; }

  // projection inputs (MODE 1 only)
  float pa0=0.f, pa1=0.f, pa2=0.f, pq0=0.f, pq1=0.f, pq2=0.f;
  if (MODE == 1) {
    int rr = (int)row0 + trow;
    pa0 = p[rr*3+0]; pa1 = p[rr*3+1]; pa2 = p[rr*3+2];
    if (y) { pq0 = p2[rr*3+0]; pq1 = p2[rr*3+1]; pq2 = p2[rr*3+2]; }
  }

  // prefetch registers; initial loads for kc=0
  uint4 px0, px1, pwa, pwb, psa, psb;
  if (MODE != 1) {
    const uint4* s = (const uint4*)(xA + (row0 + trow)*128 + tq*16);
    px0 = s[0]; px1 = s[1];
  }
  {
    const uint4* sw = (const uint4*)(w00 + trow*128 + tq*16);
    pwa = sw[0]; pwb = sw[1];
    const uint4* ss = (const uint4*)(ws0 + trow*128 + tq*16);
    psa = ss[0]; psb = ss[1];
  }

#pragma unroll 1
  for (int kc = 0; kc < 4; ++kc) {
    // ---- write staged regs (or projection) to LDS ----
    if (MODE == 1) {
      const int c0 = kc*64 + tq*16;
      unsigned t8[8];
#pragma unroll
      for (int q = 0; q < 4; ++q) {
        int c = c0 + q*4;
        float4 w0v = *(const float4*)(wp + c);
        float4 w1v = *(const float4*)(wp + 256 + c);
        float4 w2v = *(const float4*)(wp + 512 + c);
        float4 bbv = *(const float4*)(bp + c);
        float v0 = pa0*w0v.x + pa1*w1v.x + pa2*w2v.x + bbv.x;
        float v1 = pa0*w0v.y + pa1*w1v.y + pa2*w2v.y + bbv.y;
        float v2 = pa0*w0v.z + pa1*w1v.z + pa2*w2v.z + bbv.z;
        float v3 = pa0*w0v.w + pa1*w1v.w + pa2*w2v.w + bbv.w;
        if (y) {
          float4 u0 = *(const float4*)(wp2 + c);
          float4 u1 = *(const float4*)(wp2 + 256 + c);
          float4 u2 = *(const float4*)(wp2 + 512 + c);
          float4 b2 = *(const float4*)(bp2 + c);
          v0 += pq0*u0.x + pq1*u1.x + pq2*u2.x + b2.x;
          v1 += pq0*u0.y + pq1*u1.y + pq2*u2.y + b2.y;
          v2 += pq0*u0.z + pq1*u1.z + pq2*u2.z + b2.z;
          v3 += pq0*u0.w + pq1*u1.w + pq2*u2.w + b2.w;
        }
        t8[q*2]   = pack2(v0, v1);
        t8[q*2+1] = pack2(v2, v3);
      }
      uint4* d = (uint4*)(xs + trow*72 + tq*16);
      d[0] = make_uint4(t8[0], t8[1], t8[2], t8[3]);
      d[1] = make_uint4(t8[4], t8[5], t8[6], t8[7]);
    } else {
      uint4* d = (uint4*)(xs + trow*72 + tq*16);
      d[0] = px0; d[1] = px1;
    }
    { uint4* d = (uint4*)(w0s + trow*72 + tq*16); d[0] = pwa; d[1] = pwb; }
    { uint4* d = (uint4*)(wss + trow*72 + tq*16); d[0] = psa; d[1] = psb; }
    __syncthreads();
    // ---- issue next-chunk loads (latency hides under MFMA) ----
    if (kc < 3) {
      const int kn = kc + 1;
      const int k0n = (kn & 1) * 64;
      if (MODE != 1) {
        const u16* xsrcn = (kn < 2) ? xA : xB;
        const uint4* s = (const uint4*)(xsrcn + (row0 + trow)*128 + k0n + tq*16);
        px0 = s[0]; px1 = s[1];
      }
      const u16* w0srcn = (kn < 2) ? w00 : w01;
      const u16* wssrcn = (kn < 2) ? ws0 : ws1;
      const uint4* sw = (const uint4*)(w0srcn + trow*128 + k0n + tq*16);
      pwa = sw[0]; pwb = sw[1];
      const uint4* ss = (const uint4*)(wssrcn + trow*128 + k0n + tq*16);
      psa = ss[0]; psb = ss[1];
    }
    // ---- MFMA ----
#pragma unroll
    for (int kk = 0; kk < 2; ++kk) {
      const int ko = lg*8 + kk*32;
      s8v a0 = *(const s8v*)(xs + (w*16 + lm)*72 + ko);
      s8v a0r = relu8(a0);
#pragma unroll
      for (int nj = 0; nj < 8; ++nj) {
        s8v bh = *(const s8v*)(w0s + (nj*16 + lm)*72 + ko);
        acc_h[nj] = __builtin_amdgcn_mfma_f32_16x16x32_bf16(a0r, bh, acc_h[nj], 0, 0, 0);
      }
#pragma unroll
      for (int nj = 0; nj < 8; ++nj) {
        s8v bs = *(const s8v*)(wss + (nj*16 + lm)*72 + ko);
        acc_s[nj] = __builtin_amdgcn_mfma_f32_16x16x32_bf16(a0, bs, acc_s[nj], 0, 0, 0);
      }
    }
    __syncthreads();
  }
  // stage w1 halves into w0s/wss; write hidden = relu(acc_h + b0)  (hid aliases xs)
  {
    const uint4* s1 = (const uint4*)(w1c + trow*128 + tq*16);
    uint4 aa = s1[0], bb2 = s1[1];
    const uint4* s2 = (const uint4*)(w1c + trow*128 + 64 + tq*16);
    uint4 cc = s2[0], dd = s2[1];
    { uint4* d = (uint4*)(w0s + trow*72 + tq*16); d[0] = aa; d[1] = bb2; }
    { uint4* d = (uint4*)(wss + trow*72 + tq*16); d[0] = cc; d[1] = dd; }
#pragma unroll
    for (int nj = 0; nj < 8; ++nj) {
      const int col = nj*16 + lm;
      const float bv = b0[col];
#pragma unroll
      for (int r = 0; r < 4; ++r) {
        int row = w*16 + lg*4 + r;
        hid[row*136 + col] = f2bf(fmaxf(acc_h[nj][r] + bv, 0.0f));
      }
    }
  }
  __syncthreads();
  // pass 2: acc_s += hidden @ w1
#pragma unroll
  for (int kk = 0; kk < 4; ++kk) {
    const int koA = lg*8 + kk*32;
    const int koB = lg*8 + (kk & 1)*32;
    const u16* pb = (kk < 2) ? w0s : wss;
    s8v a0 = *(const s8v*)(hid + (w*16 + lm)*136 + koA);
#pragma unroll
    for (int nj = 0; nj < 8; ++nj) {
      s8v bb = *(const s8v*)(pb + (nj*16 + lm)*72 + koB);
      acc_s[nj] = __builtin_amdgcn_mfma_f32_16x16x32_bf16(a0, bb, acc_s[nj], 0, 0, 0);
    }
  }
  if (MODE != 2) {
#pragma unroll
    for (int nj = 0; nj < 8; ++nj) {
      const int col = nj*16 + lm;
      const float bv = b1[col];
#pragma unroll
      for (int r = 0; r < 4; ++r) {
        int row = w*16 + lg*4 + r;
        outp[(row0 + row)*128 + col] = f2bf(acc_s[nj][r] + bv);
      }
    }
  } else {
    __syncthreads();   // pass-2 reads of hid/w0s/wss done
    // write out into hid; stage fcw
    {
      const uint4* s1 = (const uint4*)(fcw + trow*128 + tq*16);
      uint4 aa = s1[0], bb2 = s1[1];
      const uint4* s2 = (const uint4*)(fcw + trow*128 + 64 + tq*16);
      uint4 cc = s2[0], dd = s2[1];
      { uint4* d = (uint4*)(w0s + trow*72 + tq*16); d[0] = aa; d[1] = bb2; }
      { uint4* d = (uint4*)(wss + trow*72 + tq*16); d[0] = cc; d[1] = dd; }
#pragma unroll
      for (int nj = 0; nj < 8; ++nj) {
        const int col = nj*16 + lm;
        const float bv = b1[col];
#pragma unroll
        for (int r = 0; r < 4; ++r) {
          int row = w*16 + lg*4 + r;
          hid[row*136 + col] = f2bf(acc_s[nj][r] + bv);
        }
      }
    }
    __syncthreads();
    // reuse acc_h as the FC accumulator (dead since hidden write)
#pragma unroll
    for (int j = 0; j < 8; ++j) acc_h[j] = (f4v){0,0,0,0};
#pragma unroll
    for (int kk = 0; kk < 4; ++kk) {
      const int koA = lg*8 + kk*32;
      const int koB = lg*8 + (kk & 1)*32;
      const u16* pb = (kk < 2) ? w0s : wss;
      s8v a0 = *(const s8v*)(hid + (w*16 + lm)*136 + koA);
#pragma unroll
      for (int nj = 0; nj < 8; ++nj) {
        s8v bb = *(const s8v*)(pb + (nj*16 + lm)*72 + koB);
        acc_h[nj] = __builtin_amdgcn_mfma_f32_16x16x32_bf16(a0, bb, acc_h[nj], 0, 0, 0);
      }
    }
#pragma unroll
    for (int nj = 0; nj < 8; ++nj) {
      const int col = nj*16 + lm;
      const float bv = fcb[col];
#pragma unroll
      for (int r = 0; r < 4; ++r) {
        int row = w*16 + lg*4 + r;
        outp[(row0 + row)*128 + col] = f2bf(acc_h[nj][r] + bv);
      }
    }
  }
}

// ---------------- CSR pooling (y = stream) ----------------
__global__ void k_pool(const int* __restrict__ idx, const int* __restrict__ starts,
                       const int* __restrict__ cnt32, const int* __restrict__ sorted,
                       const u16* __restrict__ netb, u16* __restrict__ pooledb) {
  const u16* net = netb + (size_t)blockIdx.y*SSTR;
  u16* pooled = pooledb + (size_t)blockIdx.y*SSTR;
  int g = blockIdx.x*256 + threadIdx.x;    // BT*16
  int sl = g & 15;
  int i = g >> 4;
  if (i >= BT) return;
  int b = i >> 13;
  float acc[8];
#pragma unroll
  for (int k = 0; k < 8; ++k) acc[k] = 0.0f;
#pragma unroll
  for (int pl = 0; pl < 3; ++pl) {
    int seg = (pl*Bn + b)*RRn + idx[pl*BT + i];
    int s = starts[seg];
    int e = s + cnt32[seg];
    float mx[8];
#pragma unroll
    for (int k = 0; k < 8; ++k) mx[k] = -3.0e38f;
    for (int j = s; j < e; ++j) {
      int jj = sorted[j];
      uint4 v = *(const uint4*)(net + (size_t)jj*128 + sl*8);
      float lo, hi;
      upk(v.x, lo, hi); mx[0] = fmaxf(mx[0], lo); mx[1] = fmaxf(mx[1], hi);
      upk(v.y, lo, hi); mx[2] = fmaxf(mx[2], lo); mx[3] = fmaxf(mx[3], hi);
      upk(v.z, lo, hi); mx[4] = fmaxf(mx[4], lo); mx[5] = fmaxf(mx[5], hi);
      upk(v.w, lo, hi); mx[6] = fmaxf(mx[6], lo); mx[7] = fmaxf(mx[7], hi);
    }
#pragma unroll
    for (int k = 0; k < 8; ++k) acc[k] += mx[k];
  }
  union { uint4 v; unsigned u[4]; } o;
#pragma unroll
  for (int k = 0; k < 4; ++k)
    o.u[k] = (unsigned)f2bf(acc[2*k]) | ((unsigned)f2bf(acc[2*k+1]) << 16);
  *(uint4*)(pooled + (size_t)i*128 + sl*8) = o.v;
}

// ---------------- scatter-mean, lane-per-bin, halves split across blockIdx.y ----
__global__ __launch_bounds__(256) void k_mean(
    const int* __restrict__ starts, const int* __restrict__ cnt32,
    const int* __restrict__ sorted, const u16* __restrict__ cbufb,
    float* __restrict__ out) {
  int W = blockIdx.x*4 + (threadIdx.x >> 6);   // 12288 wave-slots per half
  int half = blockIdx.y;
  int lane = threadIdx.x & 63;
  int grp = W & 255;
  int b = (W >> 8) & 7;
  int plq = W >> 11;            // 0..5 output plane
  int ss = plq / 3, pl = plq - 3*ss;
  int bin = grp*64 + lane;
  int seg = (pl*Bn + b)*RRn + bin;
  int c = cnt32[seg];
  int s0 = starts[seg];
  float inv = (c > 0) ? 1.0f/(float)c : 0.0f;
  const u16* cb = cbufb + (size_t)ss*SSTR;
  size_t obase = ((size_t)(plq*Bn + b)*Hn)*RRn + bin;
  float sum[64];
#pragma unroll
  for (int k = 0; k < 64; ++k) sum[k] = 0.f;
  for (int j = 0; j < c; ++j) {
    int jj = sorted[s0 + j];
    const uint4* r = (const uint4*)(cb + (size_t)jj*128 + half*64);
#pragma unroll
    for (int k = 0; k < 8; ++k) {
      uint4 q = r[k];
      float lo, hi;
      upk(q.x, lo, hi); sum[k*8+0] += lo; sum[k*8+1] += hi;
      upk(q.y, lo, hi); sum[k*8+2] += lo; sum[k*8+3] += hi;
      upk(q.z, lo, hi); sum[k*8+4] += lo; sum[k*8+5] += hi;
      upk(q.w, lo, hi); sum[k*8+6] += lo; sum[k*8+7] += hi;
    }
  }
#pragma unroll
  for (int k = 0; k < 64; ++k)
    out[obase + (size_t)(half*64 + k)*RRn] = sum[k]*inv;
}

// ---------------- host ----------------
extern "C" void kernel_launch(void* const* d_in, const int* in_sizes, int n_in,
                              void* d_out_v, int out_size, void* d_ws, size_t ws_size,
                              hipStream_t stream) {
  const float* p    = (const float*)d_in[0];
  const float* p2   = (const float*)d_in[1];
  const float* wp   = (const float*)d_in[2];
  const float* bp   = (const float*)d_in[3];
  const float* wp2  = (const float*)d_in[4];
  const float* bp2  = (const float*)d_in[5];
  const float* bw0  = (const float*)d_in[6];
  const float* bb0  = (const float*)d_in[7];
  const float* bw1  = (const float*)d_in[8];
  const float* bb1  = (const float*)d_in[9];
  const float* bws  = (const float*)d_in[10];
  const float* cw0  = (const float*)d_in[11];
  const float* cb0  = (const float*)d_in[12];
  const float* cw1  = (const float*)d_in[13];
  const float* cb1  = (const float*)d_in[14];
  const float* cws  = (const float*)d_in[15];
  const float* fcw  = (const float*)d_in[16];
  const float* fcb  = (const float*)d_in[17];
  const float* fccw = (const float*)d_in[18];
  const float* fccb = (const float*)d_in[19];
  float* out = (float*)d_out_v;

  size_t off = 0;
  auto alloc = [&](size_t bytes) -> char* {
    char* r = (char*)d_ws + off;
    off += (bytes + 255) & ~(size_t)255;
    return r;
  };
  int* idx    = (int*)alloc((size_t)3*BT*4);
  int* cnt32  = (int*)alloc((size_t)3*Bn*RRn*4);
  int* starts = (int*)alloc((size_t)3*Bn*RRn*4);
  int* cursor = (int*)alloc((size_t)3*Bn*RRn*4);
  int* sorted = (int*)alloc((size_t)3*BT*4);
  u16* arena  = (u16*)alloc((size_t)52*16384*2);
  u16* buf0   = (u16*)alloc(2*SSTR*2);   // [stream][BT][128]
  u16* buf1   = (u16*)alloc(2*SSTR*2);
  u16* bufP   = (u16*)alloc(2*SSTR*2);
  u16* cbuf   = (u16*)alloc(2*SSTR*2);
  if (off > ws_size) return;

  hipMemsetAsync(cnt32, 0, (size_t)3*Bn*RRn*4, stream);
  k_prep<<<52, 256, 0, stream>>>(bw0, bw1, bws, cw0, cw1, cws, fcw, fccw, arena);
  k_idx <<<BT/256, 256, 0, stream>>>(p, idx, cnt32);
  k_scan<<<24, 256, 0, stream>>>(cnt32, starts, cursor);
  k_fill<<<(3*BT)/256, 256, 0, stream>>>(idx, cursor, sorted);

  // block 0 with fused projection -> buf1
  k_rb<1><<<dim3(BT/128, 2), 512, 0, stream>>>(
      nullptr, nullptr, p, p2, wp, bp, wp2, bp2,
      arena, 0, 1, 15, 16, 10, 25,
      bb0, cb0, bb1, cb1, nullptr, nullptr, buf1);
  u16* net = buf1; u16* other = buf0;
  for (int blk = 1; blk < 4; ++blk) {
    k_pool<<<dim3((BT*16)/256, 2), 256, 0, stream>>>(idx, starts, cnt32, sorted, net, bufP);
    k_rb<0><<<dim3(BT/128, 2), 512, 0, stream>>>(
        net, bufP, nullptr, nullptr, nullptr, nullptr, nullptr, nullptr,
        arena, 2*blk, 2*blk+1, 15+2*blk, 16+2*blk, 10+blk, 25,
        bb0 + blk*128, cb0 + blk*128, bb1 + blk*128, cb1 + blk*128,
        nullptr, nullptr, other);
    u16* t = net; net = other; other = t;
  }
  // block 4 fused with final fc -> cbuf
  k_pool<<<dim3((BT*16)/256, 2), 256, 0, stream>>>(idx, starts, cnt32, sorted, net, bufP);
  k_rb<2><<<dim3(BT/128, 2), 512, 0, stream>>>(
      net, bufP, nullptr, nullptr, nullptr, nullptr, nullptr, nullptr,
      arena, 8, 9, 23, 24, 14, 25,
      bb0 + 4*128, cb0 + 4*128, bb1 + 4*128, cb1 + 4*128, fcb, fccb, cbuf);

  // scatter-mean: all 6 planes, halves split across y (zeros for empty bins)
  k_mean<<<dim3(3072, 2), 256, 0, stream>>>(starts, cnt32, sorted, cbuf, out);
}

// Round 13
// 517.598 us; speedup vs baseline: 1.0939x; 1.0939x over previous
//
#include <hip/hip_runtime.h>
#include <cstdint>
#include <cstddef>

#define Bn 8
#define Tn 8192
#define BT (Bn*Tn)      // 65536 points
#define Hn 128
#define RRn 16384       // 128*128 bins per plane per batch

typedef unsigned short u16;
typedef __attribute__((ext_vector_type(8))) short s8v;   // 8 bf16 (4 VGPRs)
typedef __attribute__((ext_vector_type(4))) float f4v;   // 4 f32 acc

#define SSTR ((size_t)BT*128)   // per-stream activation stride (elements)

__device__ __forceinline__ u16 f2bf(float f) {
  unsigned u = __float_as_uint(f);
  unsigned r = (u + 0x7FFF + ((u >> 16) & 1)) >> 16;   // RNE
  return (u16)r;
}
__device__ __forceinline__ unsigned pack2(float a, float b) {
  return (unsigned)f2bf(a) | ((unsigned)f2bf(b) << 16);
}

__device__ __forceinline__ s8v relu8(s8v a) {
  union { s8v s; unsigned u[4]; } x; x.s = a;
#pragma unroll
  for (int k = 0; k < 4; ++k) {
    unsigned m = ((x.u[k] & 0x80008000u) >> 15) * 0xFFFFu;
    x.u[k] &= ~m;
  }
  return x.s;
}

__device__ __forceinline__ void upk(unsigned u, float& lo, float& hi) {
  lo = __uint_as_float(u << 16);
  hi = __uint_as_float(u & 0xFFFF0000u);
}

// ---------------- index computation + histogram ----------------
__global__ void k_idx(const float* __restrict__ p, int* __restrict__ idx,
                      int* __restrict__ cnt32) {
  int i = blockIdx.x*256 + threadIdx.x;
  if (i >= BT) return;
  int b = i >> 13;
  float v0 = p[i*3+0], v1 = p[i*3+1], v2 = p[i*3+2];
  float v[3] = {v0, v1, v2};
  const int A0[3] = {0,0,1};
  const int A1[3] = {2,1,2};
#pragma unroll
  for (int pl = 0; pl < 3; ++pl) {
    float a = v[A0[pl]] / 1.001f + 0.5f;
    float bq = v[A1[pl]] / 1.001f + 0.5f;
    a = fminf(fmaxf(a, 0.0f), 0.999f);
    bq = fminf(fmaxf(bq, 0.0f), 0.999f);
    int ga = (int)floorf(a * 128.0f);
    int gb = (int)floorf(bq * 128.0f);
    int bin = ga + 128*gb;
    idx[pl*BT + i] = bin;
    atomicAdd(&cnt32[(pl*Bn + b)*RRn + bin], 1);
  }
}

// ---------------- CSR build ----------------
__global__ void k_scan(const int* __restrict__ cnt32, int* __restrict__ starts,
                       int* __restrict__ cursor) {
  int seg = blockIdx.x;                 // 0..23
  const int* c = cnt32 + seg*RRn;
  int* st = starts + seg*RRn;
  int* cu = cursor + seg*RRn;
  int t = threadIdx.x;
  __shared__ int part[256];
  int base = t*64;
  int sum = 0;
#pragma unroll 8
  for (int j = 0; j < 64; ++j) sum += c[base+j];
  part[t] = sum; __syncthreads();
  for (int ofs = 1; ofs < 256; ofs <<= 1) {
    int v = (t >= ofs) ? part[t-ofs] : 0;
    __syncthreads();
    part[t] += v;
    __syncthreads();
  }
  int run = (t ? part[t-1] : 0) + seg*Tn;
#pragma unroll 8
  for (int j = 0; j < 64; ++j) { st[base+j] = run; cu[base+j] = run; run += c[base+j]; }
}

__global__ void k_fill(const int* __restrict__ idx, int* __restrict__ cursor,
                       int* __restrict__ sorted) {
  int g = blockIdx.x*256 + threadIdx.x;
  if (g >= 3*BT) return;
  int pl = g >> 16, i = g & (BT-1);
  int b = i >> 13;
  int pos = atomicAdd(&cursor[(pl*Bn + b)*RRn + idx[g]], 1);
  sorted[pos] = i;
}

// ---------------- weight prep: f32 [k][n] -> bf16 [n][k], 52 chunks of 128x128 ----
__global__ void k_prep(const float* __restrict__ bw0, const float* __restrict__ bw1,
                       const float* __restrict__ bws, const float* __restrict__ cw0,
                       const float* __restrict__ cw1, const float* __restrict__ cws,
                       const float* __restrict__ fcw, const float* __restrict__ fccw,
                       u16* __restrict__ arena) {
  int c = blockIdx.x;            // 0..51
  int s = c / 26, r = c % 26;
  const float* base;
  if (r < 10)      base = (s ? cw0 : bw0) + (size_t)(r >> 1)*32768 + (size_t)(r & 1)*16384;
  else if (r < 15) base = (s ? cw1 : bw1) + (size_t)(r - 10)*16384;
  else if (r < 25) base = (s ? cws : bws) + (size_t)((r - 15) >> 1)*32768 + (size_t)((r - 15) & 1)*16384;
  else             base = s ? fccw : fcw;
  __shared__ u16 ld[128*130];
#pragma unroll 4
  for (int it = 0; it < 64; ++it) {
    int lin = it*256 + threadIdx.x;
    int k = lin >> 7, n = lin & 127;
    ld[k*130 + n] = f2bf(base[lin]);
  }
  __syncthreads();
  u16* dst = arena + (size_t)c*16384;
#pragma unroll 4
  for (int it = 0; it < 64; ++it) {
    int lin = it*256 + threadIdx.x;
    int n = lin >> 7, k = lin & 127;
    dst[lin] = ld[k*130 + n];
  }
}

// ---------------- fused ResNet block, 256 rows/block, async-staged ----------------
// MODE 1: block 0 -- x = projection computed in staging.
// MODE 0: middle  -- x = [xA | xB] from global (xB = pooled from k_pool).
// MODE 2: final   -- like 0, plus fused final FC.
// hidden = relu( relu(x) @ w0 + b0 )   (LDS only)
// out    = x @ ws + hidden @ w1 + b1   [; cout = out @ fcw + fcb in MODE 2]
template<int MODE>
__global__ __launch_bounds__(512, 2) void k_rb(
    const u16* __restrict__ xAb, const u16* __restrict__ xBb,
    const float* __restrict__ p, const float* __restrict__ p2,
    const float* __restrict__ wp, const float* __restrict__ bp,
    const float* __restrict__ wp2, const float* __restrict__ bp2,
    const u16* __restrict__ arena,
    int cw00, int cw01, int cws0, int cws1, int cw1c, int cfcw,
    const float* __restrict__ b0g, const float* __restrict__ b0c,
    const float* __restrict__ b1g, const float* __restrict__ b1c,
    const float* __restrict__ fcbg, const float* __restrict__ fcbc,
    u16* __restrict__ outb)
{
  const int y = blockIdx.y;
  const u16* ar = arena + (size_t)y*26*16384;
  const u16* w00 = ar + (size_t)cw00*16384;
  const u16* w01 = ar + (size_t)cw01*16384;
  const u16* ws0 = ar + (size_t)cws0*16384;
  const u16* ws1 = ar + (size_t)cws1*16384;
  const u16* w1c = ar + (size_t)cw1c*16384;
  const u16* fcw = ar + (size_t)cfcw*16384;
  const float* b0 = y ? b0c : b0g;
  const float* b1 = y ? b1c : b1g;
  const float* fcb = y ? fcbc : fcbg;
  const u16* xA = xAb + (size_t)y*SSTR;
  const u16* xB = xBb + (size_t)y*SSTR;
  u16* outp = outb + (size_t)y*SSTR;

  __shared__ u16 xs [256*72];   // [row][k-chunk 64 pad 72]
  __shared__ u16 w0s[128*72];   // fc0 weight chunk [n][k]
  __shared__ u16 wss[128*72];   // shortcut weight chunk [n][k]
  __shared__ u16 hid[256*136];  // hidden / out rows
  const int tid = threadIdx.x;
  const size_t row0 = (size_t)blockIdx.x * 256;
  const int l = tid & 63, w = tid >> 6;     // 8 waves, 32 rows each
  const int lm = l & 15, lg = l >> 4;
  const int trow = tid >> 1, th = tid & 1;  // x staging: 64B/thread
  const int wn = tid >> 2, wq = tid & 3;    // w staging: 32B/thread/buffer

  f4v acc_h[2][8], acc_s[2][8];
#pragma unroll
  for (int mi = 0; mi < 2; ++mi)
#pragma unroll
    for (int j = 0; j < 8; ++j) { acc_h[mi][j] = (f4v){0,0,0,0}; acc_s[mi][j] = (f4v){0,0,0,0}; }

  // projection inputs (MODE 1 only)
  float pa0=0.f, pa1=0.f, pa2=0.f, pq0=0.f, pq1=0.f, pq2=0.f;
  if (MODE == 1) {
    int rr = (int)row0 + trow;
    pa0 = p[rr*3+0]; pa1 = p[rr*3+1]; pa2 = p[rr*3+2];
    if (y) { pq0 = p2[rr*3+0]; pq1 = p2[rr*3+1]; pq2 = p2[rr*3+2]; }
  }

  // prefetch registers
  uint4 px0, px1, px2, px3, pwa, pwb, psa, psb;
  // initial loads for kc=0
  if (MODE != 1) {
    const uint4* s = (const uint4*)(xA + (row0 + trow)*128 + th*32);
    px0 = s[0]; px1 = s[1]; px2 = s[2]; px3 = s[3];
  }
  {
    const uint4* sw = (const uint4*)(w00 + wn*128 + wq*16);
    pwa = sw[0]; pwb = sw[1];
    const uint4* ss = (const uint4*)(ws0 + wn*128 + wq*16);
    psa = ss[0]; psb = ss[1];
  }

#pragma unroll 1
  for (int kc = 0; kc < 4; ++kc) {
    // ---- write staged regs (or projection) to LDS ----
    if (MODE == 1) {
      const int c0 = kc*64 + th*32;
      unsigned t16[16];
#pragma unroll
      for (int q = 0; q < 8; ++q) {
        int c = c0 + q*4;
        float4 w0v = *(const float4*)(wp + c);
        float4 w1v = *(const float4*)(wp + 256 + c);
        float4 w2v = *(const float4*)(wp + 512 + c);
        float4 bbv = *(const float4*)(bp + c);
        float v0 = pa0*w0v.x + pa1*w1v.x + pa2*w2v.x + bbv.x;
        float v1 = pa0*w0v.y + pa1*w1v.y + pa2*w2v.y + bbv.y;
        float v2 = pa0*w0v.z + pa1*w1v.z + pa2*w2v.z + bbv.z;
        float v3 = pa0*w0v.w + pa1*w1v.w + pa2*w2v.w + bbv.w;
        if (y) {
          float4 u0 = *(const float4*)(wp2 + c);
          float4 u1 = *(const float4*)(wp2 + 256 + c);
          float4 u2 = *(const float4*)(wp2 + 512 + c);
          float4 b2 = *(const float4*)(bp2 + c);
          v0 += pq0*u0.x + pq1*u1.x + pq2*u2.x + b2.x;
          v1 += pq0*u0.y + pq1*u1.y + pq2*u2.y + b2.y;
          v2 += pq0*u0.z + pq1*u1.z + pq2*u2.z + b2.z;
          v3 += pq0*u0.w + pq1*u1.w + pq2*u2.w + b2.w;
        }
        t16[q*2]   = pack2(v0, v1);
        t16[q*2+1] = pack2(v2, v3);
      }
      uint4* d = (uint4*)(xs + trow*72 + th*32);
      d[0] = make_uint4(t16[0], t16[1], t16[2], t16[3]);
      d[1] = make_uint4(t16[4], t16[5], t16[6], t16[7]);
      d[2] = make_uint4(t16[8], t16[9], t16[10], t16[11]);
      d[3] = make_uint4(t16[12], t16[13], t16[14], t16[15]);
    } else {
      uint4* d = (uint4*)(xs + trow*72 + th*32);
      d[0] = px0; d[1] = px1; d[2] = px2; d[3] = px3;
    }
    { uint4* d = (uint4*)(w0s + wn*72 + wq*16); d[0] = pwa; d[1] = pwb; }
    { uint4* d = (uint4*)(wss + wn*72 + wq*16); d[0] = psa; d[1] = psb; }
    __syncthreads();
    // ---- issue next-chunk loads (latency hides under MFMA) ----
    if (kc < 3) {
      const int kn = kc + 1;
      const int k0n = (kn & 1) * 64;
      if (MODE != 1) {
        const u16* xsrcn = (kn < 2) ? xA : xB;
        const uint4* s = (const uint4*)(xsrcn + (row0 + trow)*128 + k0n + th*32);
        px0 = s[0]; px1 = s[1]; px2 = s[2]; px3 = s[3];
      }
      const u16* w0srcn = (kn < 2) ? w00 : w01;
      const u16* wssrcn = (kn < 2) ? ws0 : ws1;
      const uint4* sw = (const uint4*)(w0srcn + wn*128 + k0n + wq*16);
      pwa = sw[0]; pwb = sw[1];
      const uint4* ss = (const uint4*)(wssrcn + wn*128 + k0n + wq*16);
      psa = ss[0]; psb = ss[1];
    }
    // ---- MFMA ----
#pragma unroll
    for (int kk = 0; kk < 2; ++kk) {
      const int ko = lg*8 + kk*32;
      s8v a0 = *(const s8v*)(xs + (w*32 + lm)*72 + ko);
      s8v a1 = *(const s8v*)(xs + (w*32 + 16 + lm)*72 + ko);
      s8v a0r = relu8(a0), a1r = relu8(a1);
#pragma unroll
      for (int nj = 0; nj < 8; ++nj) {
        s8v bh = *(const s8v*)(w0s + (nj*16 + lm)*72 + ko);
        acc_h[0][nj] = __builtin_amdgcn_mfma_f32_16x16x32_bf16(a0r, bh, acc_h[0][nj], 0, 0, 0);
        acc_h[1][nj] = __builtin_amdgcn_mfma_f32_16x16x32_bf16(a1r, bh, acc_h[1][nj], 0, 0, 0);
      }
#pragma unroll
      for (int nj = 0; nj < 8; ++nj) {
        s8v bs = *(const s8v*)(wss + (nj*16 + lm)*72 + ko);
        acc_s[0][nj] = __builtin_amdgcn_mfma_f32_16x16x32_bf16(a0, bs, acc_s[0][nj], 0, 0, 0);
        acc_s[1][nj] = __builtin_amdgcn_mfma_f32_16x16x32_bf16(a1, bs, acc_s[1][nj], 0, 0, 0);
      }
    }
    __syncthreads();
  }
  // stage w1 halves into w0s/wss; write hidden = relu(acc_h + b0)
  {
    const uint4* s1 = (const uint4*)(w1c + wn*128 + wq*16);
    uint4 aa = s1[0], bb2 = s1[1];
    const uint4* s2 = (const uint4*)(w1c + wn*128 + 64 + wq*16);
    uint4 cc = s2[0], dd = s2[1];
    { uint4* d = (uint4*)(w0s + wn*72 + wq*16); d[0] = aa; d[1] = bb2; }
    { uint4* d = (uint4*)(wss + wn*72 + wq*16); d[0] = cc; d[1] = dd; }
#pragma unroll
    for (int mi = 0; mi < 2; ++mi)
#pragma unroll
      for (int nj = 0; nj < 8; ++nj) {
        const int col = nj*16 + lm;
        const float bv = b0[col];
#pragma unroll
        for (int r = 0; r < 4; ++r) {
          int row = w*32 + mi*16 + lg*4 + r;
          hid[row*136 + col] = f2bf(fmaxf(acc_h[mi][nj][r] + bv, 0.0f));
        }
      }
  }
  __syncthreads();
  // pass 2: acc_s += hidden @ w1
#pragma unroll
  for (int kk = 0; kk < 4; ++kk) {
    const int koA = lg*8 + kk*32;
    const int koB = lg*8 + (kk & 1)*32;
    const u16* pb = (kk < 2) ? w0s : wss;
    s8v a0 = *(const s8v*)(hid + (w*32 + lm)*136 + koA);
    s8v a1 = *(const s8v*)(hid + (w*32 + 16 + lm)*136 + koA);
#pragma unroll
    for (int nj = 0; nj < 8; ++nj) {
      s8v bb = *(const s8v*)(pb + (nj*16 + lm)*72 + koB);
      acc_s[0][nj] = __builtin_amdgcn_mfma_f32_16x16x32_bf16(a0, bb, acc_s[0][nj], 0, 0, 0);
      acc_s[1][nj] = __builtin_amdgcn_mfma_f32_16x16x32_bf16(a1, bb, acc_s[1][nj], 0, 0, 0);
    }
  }
  if (MODE != 2) {
#pragma unroll
    for (int mi = 0; mi < 2; ++mi)
#pragma unroll
      for (int nj = 0; nj < 8; ++nj) {
        const int col = nj*16 + lm;
        const float bv = b1[col];
#pragma unroll
        for (int r = 0; r < 4; ++r) {
          int row = w*32 + mi*16 + lg*4 + r;
          outp[(row0 + row)*128 + col] = f2bf(acc_s[mi][nj][r] + bv);
        }
      }
  } else {
    __syncthreads();   // pass-2 reads of hid/w0s/wss done
    // write out into hid; stage fcw
    {
      const uint4* s1 = (const uint4*)(fcw + wn*128 + wq*16);
      uint4 aa = s1[0], bb2 = s1[1];
      const uint4* s2 = (const uint4*)(fcw + wn*128 + 64 + wq*16);
      uint4 cc = s2[0], dd = s2[1];
      { uint4* d = (uint4*)(w0s + wn*72 + wq*16); d[0] = aa; d[1] = bb2; }
      { uint4* d = (uint4*)(wss + wn*72 + wq*16); d[0] = cc; d[1] = dd; }
#pragma unroll
      for (int mi = 0; mi < 2; ++mi)
#pragma unroll
        for (int nj = 0; nj < 8; ++nj) {
          const int col = nj*16 + lm;
          const float bv = b1[col];
#pragma unroll
          for (int r = 0; r < 4; ++r) {
            int row = w*32 + mi*16 + lg*4 + r;
            hid[row*136 + col] = f2bf(acc_s[mi][nj][r] + bv);
          }
        }
    }
    __syncthreads();
    f4v accf[2][8];
#pragma unroll
    for (int mi = 0; mi < 2; ++mi)
#pragma unroll
      for (int j = 0; j < 8; ++j) accf[mi][j] = (f4v){0,0,0,0};
#pragma unroll
    for (int kk = 0; kk < 4; ++kk) {
      const int koA = lg*8 + kk*32;
      const int koB = lg*8 + (kk & 1)*32;
      const u16* pb = (kk < 2) ? w0s : wss;
      s8v a0 = *(const s8v*)(hid + (w*32 + lm)*136 + koA);
      s8v a1 = *(const s8v*)(hid + (w*32 + 16 + lm)*136 + koA);
#pragma unroll
      for (int nj = 0; nj < 8; ++nj) {
        s8v bb = *(const s8v*)(pb + (nj*16 + lm)*72 + koB);
        accf[0][nj] = __builtin_amdgcn_mfma_f32_16x16x32_bf16(a0, bb, accf[0][nj], 0, 0, 0);
        accf[1][nj] = __builtin_amdgcn_mfma_f32_16x16x32_bf16(a1, bb, accf[1][nj], 0, 0, 0);
      }
    }
#pragma unroll
    for (int mi = 0; mi < 2; ++mi)
#pragma unroll
      for (int nj = 0; nj < 8; ++nj) {
        const int col = nj*16 + lm;
        const float bv = fcb[col];
#pragma unroll
        for (int r = 0; r < 4; ++r) {
          int row = w*32 + mi*16 + lg*4 + r;
          outp[(row0 + row)*128 + col] = f2bf(accf[mi][nj][r] + bv);
        }
      }
  }
}

// ---------------- CSR pooling (y = stream) ----------------
__global__ void k_pool(const int* __restrict__ idx, const int* __restrict__ starts,
                       const int* __restrict__ cnt32, const int* __restrict__ sorted,
                       const u16* __restrict__ netb, u16* __restrict__ pooledb) {
  const u16* net = netb + (size_t)blockIdx.y*SSTR;
  u16* pooled = pooledb + (size_t)blockIdx.y*SSTR;
  int g = blockIdx.x*256 + threadIdx.x;    // BT*16
  int sl = g & 15;
  int i = g >> 4;
  if (i >= BT) return;
  int b = i >> 13;
  float acc[8];
#pragma unroll
  for (int k = 0; k < 8; ++k) acc[k] = 0.0f;
#pragma unroll
  for (int pl = 0; pl < 3; ++pl) {
    int seg = (pl*Bn + b)*RRn + idx[pl*BT + i];
    int s = starts[seg];
    int e = s + cnt32[seg];
    float mx[8];
#pragma unroll
    for (int k = 0; k < 8; ++k) mx[k] = -3.0e38f;
    for (int j = s; j < e; ++j) {
      int jj = sorted[j];
      uint4 v = *(const uint4*)(net + (size_t)jj*128 + sl*8);
      float lo, hi;
      upk(v.x, lo, hi); mx[0] = fmaxf(mx[0], lo); mx[1] = fmaxf(mx[1], hi);
      upk(v.y, lo, hi); mx[2] = fmaxf(mx[2], lo); mx[3] = fmaxf(mx[3], hi);
      upk(v.z, lo, hi); mx[4] = fmaxf(mx[4], lo); mx[5] = fmaxf(mx[5], hi);
      upk(v.w, lo, hi); mx[6] = fmaxf(mx[6], lo); mx[7] = fmaxf(mx[7], hi);
    }
#pragma unroll
    for (int k = 0; k < 8; ++k) acc[k] += mx[k];
  }
  union { uint4 v; unsigned u[4]; } o;
#pragma unroll
  for (int k = 0; k < 4; ++k)
    o.u[k] = (unsigned)f2bf(acc[2*k]) | ((unsigned)f2bf(acc[2*k+1]) << 16);
  *(uint4*)(pooled + (size_t)i*128 + sl*8) = o.v;
}

// ---------------- scatter-mean, lane-per-bin, halves split across blockIdx.y ----
// Output stores are non-temporal: written once, never re-read -> don't pollute LLC.
__global__ __launch_bounds__(256) void k_mean(
    const int* __restrict__ starts, const int* __restrict__ cnt32,
    const int* __restrict__ sorted, const u16* __restrict__ cbufb,
    float* __restrict__ out) {
  int W = blockIdx.x*4 + (threadIdx.x >> 6);   // 12288 wave-slots per half
  int half = blockIdx.y;
  int lane = threadIdx.x & 63;
  int grp = W & 255;
  int b = (W >> 8) & 7;
  int plq = W >> 11;            // 0..5 output plane
  int ss = plq / 3, pl = plq - 3*ss;
  int bin = grp*64 + lane;
  int seg = (pl*Bn + b)*RRn + bin;
  int c = cnt32[seg];
  int s0 = starts[seg];
  float inv = (c > 0) ? 1.0f/(float)c : 0.0f;
  const u16* cb = cbufb + (size_t)ss*SSTR;
  size_t obase = ((size_t)(plq*Bn + b)*Hn)*RRn + bin;
  float sum[64];
#pragma unroll
  for (int k = 0; k < 64; ++k) sum[k] = 0.f;
  for (int j = 0; j < c; ++j) {
    int jj = sorted[s0 + j];
    const uint4* r = (const uint4*)(cb + (size_t)jj*128 + half*64);
#pragma unroll
    for (int k = 0; k < 8; ++k) {
      uint4 q = r[k];
      float lo, hi;
      upk(q.x, lo, hi); sum[k*8+0] += lo; sum[k*8+1] += hi;
      upk(q.y, lo, hi); sum[k*8+2] += lo; sum[k*8+3] += hi;
      upk(q.z, lo, hi); sum[k*8+4] += lo; sum[k*8+5] += hi;
      upk(q.w, lo, hi); sum[k*8+6] += lo; sum[k*8+7] += hi;
    }
  }
#pragma unroll
  for (int k = 0; k < 64; ++k)
    __builtin_nontemporal_store(sum[k]*inv, &out[obase + (size_t)(half*64 + k)*RRn]);
}

// ---------------- host ----------------
extern "C" void kernel_launch(void* const* d_in, const int* in_sizes, int n_in,
                              void* d_out_v, int out_size, void* d_ws, size_t ws_size,
                              hipStream_t stream) {
  const float* p    = (const float*)d_in[0];
  const float* p2   = (const float*)d_in[1];
  const float* wp   = (const float*)d_in[2];
  const float* bp   = (const float*)d_in[3];
  const float* wp2  = (const float*)d_in[4];
  const float* bp2  = (const float*)d_in[5];
  const float* bw0  = (const float*)d_in[6];
  const float* bb0  = (const float*)d_in[7];
  const float* bw1  = (const float*)d_in[8];
  const float* bb1  = (const float*)d_in[9];
  const float* bws  = (const float*)d_in[10];
  const float* cw0  = (const float*)d_in[11];
  const float* cb0  = (const float*)d_in[12];
  const float* cw1  = (const float*)d_in[13];
  const float* cb1  = (const float*)d_in[14];
  const float* cws  = (const float*)d_in[15];
  const float* fcw  = (const float*)d_in[16];
  const float* fcb  = (const float*)d_in[17];
  const float* fccw = (const float*)d_in[18];
  const float* fccb = (const float*)d_in[19];
  float* out = (float*)d_out_v;

  size_t off = 0;
  auto alloc = [&](size_t bytes) -> char* {
    char* r = (char*)d_ws + off;
    off += (bytes + 255) & ~(size_t)255;
    return r;
  };
  int* idx    = (int*)alloc((size_t)3*BT*4);
  int* cnt32  = (int*)alloc((size_t)3*Bn*RRn*4);
  int* starts = (int*)alloc((size_t)3*Bn*RRn*4);
  int* cursor = (int*)alloc((size_t)3*Bn*RRn*4);
  int* sorted = (int*)alloc((size_t)3*BT*4);
  u16* arena  = (u16*)alloc((size_t)52*16384*2);
  u16* buf0   = (u16*)alloc(2*SSTR*2);   // [stream][BT][128]
  u16* buf1   = (u16*)alloc(2*SSTR*2);
  u16* bufP   = (u16*)alloc(2*SSTR*2);
  u16* cbuf   = (u16*)alloc(2*SSTR*2);
  if (off > ws_size) return;

  hipMemsetAsync(cnt32, 0, (size_t)3*Bn*RRn*4, stream);
  k_prep<<<52, 256, 0, stream>>>(bw0, bw1, bws, cw0, cw1, cws, fcw, fccw, arena);
  k_idx <<<BT/256, 256, 0, stream>>>(p, idx, cnt32);
  k_scan<<<24, 256, 0, stream>>>(cnt32, starts, cursor);
  k_fill<<<(3*BT)/256, 256, 0, stream>>>(idx, cursor, sorted);

  // block 0 with fused projection -> buf1
  k_rb<1><<<dim3(BT/256, 2), 512, 0, stream>>>(
      nullptr, nullptr, p, p2, wp, bp, wp2, bp2,
      arena, 0, 1, 15, 16, 10, 25,
      bb0, cb0, bb1, cb1, nullptr, nullptr, buf1);
  u16* net = buf1; u16* other = buf0;
  for (int blk = 1; blk < 4; ++blk) {
    k_pool<<<dim3((BT*16)/256, 2), 256, 0, stream>>>(idx, starts, cnt32, sorted, net, bufP);
    k_rb<0><<<dim3(BT/256, 2), 512, 0, stream>>>(
        net, bufP, nullptr, nullptr, nullptr, nullptr, nullptr, nullptr,
        arena, 2*blk, 2*blk+1, 15+2*blk, 16+2*blk, 10+blk, 25,
        bb0 + blk*128, cb0 + blk*128, bb1 + blk*128, cb1 + blk*128,
        nullptr, nullptr, other);
    u16* t = net; net = other; other = t;
  }
  // block 4 fused with final fc -> cbuf
  k_pool<<<dim3((BT*16)/256, 2), 256, 0, stream>>>(idx, starts, cnt32, sorted, net, bufP);
  k_rb<2><<<dim3(BT/256, 2), 512, 0, stream>>>(
      net, bufP, nullptr, nullptr, nullptr, nullptr, nullptr, nullptr,
      arena, 8, 9, 23, 24, 14, 25,
      bb0 + 4*128, cb0 + 4*128, bb1 + 4*128, cb1 + 4*128, fcb, fccb, cbuf);

  // scatter-mean: all 6 planes, halves split across y (zeros for empty bins)
  k_mean<<<dim3(3072, 2), 256, 0, stream>>>(starts, cnt32, sorted, cbuf, out);
}